// Round 2
// baseline (51.093 us; speedup 1.0000x reference)
//
#include <hip/hip_runtime.h>
#include <math.h>

// Problem constants (fixed shapes from reference)
#define BATCH   8
#define HGRID   64
#define WGRID   64
#define DDIM    256
#define NPTS    1024
#define ROWS    65          // HGRID + 1 (NaN pad row 0)
#define COLS    65
#define KWIN    15          // (2*R_WIN+1)*(2*C_WIN+1) = 3*5
#define BN      (BATCH*NPTS)

// ---------------------------------------------------------------------------
// Kernel 1: proj[m,d] = sum_c c_t[m,c] * W_a[c,d]   (m = b*N+n)
// fp32 tiled GEMM, 64x64 tile, K-tile 64, 256 threads, 4x4 micro-tile/thread.
// A-tile stored TRANSPOSED in LDS ([k][row]) so the inner loop does
// 2x ds_read_b128 instead of 8x ds_read_b32. Pitch 68 floats = 272 B keeps
// 16B alignment for float4 reads and breaks power-of-2 bank stride.
// ---------------------------------------------------------------------------
__global__ __launch_bounds__(256) void proj_gemm(const float* __restrict__ C,
                                                 const float* __restrict__ Wa,
                                                 float* __restrict__ P) {
    __shared__ __align__(16) float As[64][68];   // As[k][row]  (A transposed)
    __shared__ __align__(16) float Bs[64][68];   // Bs[k][col]
    const int t  = threadIdx.x;
    const int m0 = blockIdx.x * 64;
    const int n0 = blockIdx.y * 64;
    const int tx = t & 15;
    const int ty = t >> 4;
    float acc[4][4] = {};
    for (int kt = 0; kt < DDIM; kt += 64) {
        #pragma unroll
        for (int rep = 0; rep < 4; ++rep) {
            int f   = rep * 256 + t;     // float4 slot 0..1023
            int row = f >> 4;            // 16 float4 per 64-float row
            int c4  = (f & 15) * 4;
            float4 av = *reinterpret_cast<const float4*>(&C[(m0 + row) * DDIM + kt + c4]);
            As[c4 + 0][row] = av.x;
            As[c4 + 1][row] = av.y;
            As[c4 + 2][row] = av.z;
            As[c4 + 3][row] = av.w;
            *reinterpret_cast<float4*>(&Bs[row][c4]) =
                *reinterpret_cast<const float4*>(&Wa[(kt + row) * DDIM + n0 + c4]);
        }
        __syncthreads();
        #pragma unroll
        for (int k = 0; k < 64; ++k) {
            float4 a = *reinterpret_cast<float4*>(&As[k][ty * 4]);
            float4 b = *reinterpret_cast<float4*>(&Bs[k][tx * 4]);
            acc[0][0] += a.x * b.x; acc[0][1] += a.x * b.y; acc[0][2] += a.x * b.z; acc[0][3] += a.x * b.w;
            acc[1][0] += a.y * b.x; acc[1][1] += a.y * b.y; acc[1][2] += a.y * b.z; acc[1][3] += a.y * b.w;
            acc[2][0] += a.z * b.x; acc[2][1] += a.z * b.y; acc[2][2] += a.z * b.z; acc[2][3] += a.z * b.w;
            acc[3][0] += a.w * b.x; acc[3][1] += a.w * b.y; acc[3][2] += a.w * b.z; acc[3][3] += a.w * b.w;
        }
        __syncthreads();
    }
    #pragma unroll
    for (int i = 0; i < 4; ++i) {
        float4 v = make_float4(acc[i][0], acc[i][1], acc[i][2], acc[i][3]);
        *reinterpret_cast<float4*>(&P[(m0 + ty * 4 + i) * DDIM + n0 + tx * 4]) = v;
    }
}

// ---------------------------------------------------------------------------
// Kernel 2: one wave per (b,n). Lane owns d = lane*4..+3 (float4).
// VGPR diet: gathered q rows packed to bf16 (2 per VGPR via v_perm),
// re[3]/ce[5] factors instead of expw[15], __expf not libm expf.
// Target <=128 VGPR -> 4 waves/SIMD.
// ---------------------------------------------------------------------------
__global__ __launch_bounds__(256, 4) void local_attn(const float* __restrict__ q,
                                                     const float* __restrict__ p_t,
                                                     const float* __restrict__ proj,
                                                     float* __restrict__ out) {
    const int wave = threadIdx.x >> 6;
    const int lane = threadIdx.x & 63;
    const int pid  = blockIdx.x * 4 + wave;      // 0..8191
    const int b    = pid >> 10;                  // / NPTS
    const float2 pp = *reinterpret_cast<const float2*>(&p_t[pid * 2]);
    const float p0f = pp.x;
    const float p1f = pp.y;
    const int p0 = (int)p0f;                     // truncation == floor (nonneg)
    const int p1 = (int)p1f;

    const float4 pr = *reinterpret_cast<const float4*>(&proj[(size_t)pid * DDIM + lane * 4]);

    float score[KWIN];
    unsigned qp0[KWIN], qp1[KWIN];   // bf16-packed qg: (hi16(y)<<16)|hi16(x), (w,z)
    float re[3], ce[5];
    int rowidx[3], colidx[5];
    unsigned vmask = 0;

    #pragma unroll
    for (int i = 0; i < 3; ++i) {
        int rr = p0 + i;                          // in [0,64]; clamp for safety
        rr = rr > ROWS ? ROWS : rr;
        rr = (rr == ROWS) ? 0 : rr;               // % ROWS
        rowidx[i] = rr;
        const float rf = (float)(rr - 1 > 0 ? rr - 1 : 0);
        const float dr = rf - p0f;                // / R_WIN (=1)
        re[i] = __expf(-2.0f * dr * dr);
    }
    #pragma unroll
    for (int j = 0; j < 5; ++j) {
        int cc = p1 + j - 1;
        cc = cc < 0 ? 0 : (cc > COLS ? COLS : cc);
        cc = (cc == COLS) ? 0 : cc;               // % COLS
        colidx[j] = cc;
        const float cf = (float)(cc - 1 > 0 ? cc - 1 : 0);
        const float dc = (cf - p1f) * 0.5f;       // / C_WIN (=2)
        ce[j] = __expf(-2.0f * dc * dc);
    }

    // Pass 1: gather + dot partials + bf16 pack (loads all independent -> ILP)
    #pragma unroll
    for (int i = 0; i < 3; ++i) {
        #pragma unroll
        for (int j = 0; j < 5; ++j) {
            const int k  = i * 5 + j;
            const int rr = rowidx[i];
            const int cc = colidx[j];
            const bool valid = (rr != 0) && (cc != 0);    // wave-uniform
            float s = 0.f;
            unsigned a0 = 0u, a1 = 0u;
            if (valid) {
                const float4 v = *reinterpret_cast<const float4*>(
                    &q[((size_t)((b * HGRID + rr - 1) * WGRID + cc - 1)) * DDIM + lane * 4]);
                s = v.x * pr.x + v.y * pr.y + v.z * pr.z + v.w * pr.w;
                a0 = __builtin_amdgcn_perm(__float_as_uint(v.y), __float_as_uint(v.x), 0x07060302u);
                a1 = __builtin_amdgcn_perm(__float_as_uint(v.w), __float_as_uint(v.z), 0x07060302u);
                vmask |= (1u << k);
            }
            qp0[k] = a0;
            qp1[k] = a1;
            score[k] = s;
        }
    }

    // Pass 2: wave-64 butterfly reduce each score
    #pragma unroll
    for (int k = 0; k < KWIN; ++k) {
        float s = score[k];
        #pragma unroll
        for (int off = 32; off; off >>= 1) s += __shfl_xor(s, off, 64);
        score[k] = ((vmask >> k) & 1u) ? s : -INFINITY;
    }

    // Softmax over K=15 (replicated identically across lanes)
    float mx = score[0];
    #pragma unroll
    for (int k = 1; k < KWIN; ++k) mx = fmaxf(mx, score[k]);
    float sum = 0.f;
    #pragma unroll
    for (int k = 0; k < KWIN; ++k) {
        const float e = __expf(score[k] - mx);
        score[k] = e;
        sum += e;
    }
    const float inv = 1.0f / sum;

    float ox = 0.f, oy = 0.f, oz = 0.f, ow = 0.f;
    #pragma unroll
    for (int i = 0; i < 3; ++i) {
        #pragma unroll
        for (int j = 0; j < 5; ++j) {
            const int k = i * 5 + j;
            const float wk = score[k] * inv * re[i] * ce[j];
            const float x = __uint_as_float(qp0[k] << 16);
            const float y = __uint_as_float(qp0[k] & 0xFFFF0000u);
            const float z = __uint_as_float(qp1[k] << 16);
            const float w = __uint_as_float(qp1[k] & 0xFFFF0000u);
            ox += wk * x;
            oy += wk * y;
            oz += wk * z;
            ow += wk * w;
        }
    }
    *reinterpret_cast<float4*>(&out[(size_t)pid * DDIM + lane * 4]) =
        make_float4(ox, oy, oz, ow);
}

// ---------------------------------------------------------------------------
extern "C" void kernel_launch(void* const* d_in, const int* in_sizes, int n_in,
                              void* d_out, int out_size, void* d_ws, size_t ws_size,
                              hipStream_t stream) {
    const float* q   = (const float*)d_in[0];
    const float* c_t = (const float*)d_in[1];
    const float* p_t = (const float*)d_in[2];
    const float* W_a = (const float*)d_in[3];
    float* out  = (float*)d_out;
    float* proj = (float*)d_ws;                 // BN*DDIM*4 = 8 MB scratch

    dim3 gemm_grid(BN / 64, DDIM / 64);         // 128 x 4
    proj_gemm<<<gemm_grid, 256, 0, stream>>>(c_t, W_a, proj);

    local_attn<<<BN / 4, 256, 0, stream>>>(q, p_t, proj, out);
}